// Round 11
// baseline (190.626 us; speedup 1.0000x reference)
//
#include <hip/hip_runtime.h>
#include <math.h>

#define TPB 256
#define NB  8     // batches (elements) per thread; block owns TPB*NB = 2048 elements

// 12-byte element record; loads compile to global_load_dwordx3
struct __align__(4) f3 { float x, y, z; };

// R = I + a*K + b*K^2 with K=skew(v), K^2 = v v^T - th^2 I
// => R = (1 - b*th^2) I + b * v v^T + a * K   (matches reference incl. small-angle branch)
__device__ __forceinline__ void rodrigues(float v0, float v1, float v2, float R[9]) {
    float th2 = v0 * v0 + v1 * v1 + v2 * v2;
    float th  = sqrtf(th2);
    float s, c;
    sincosf(th, &s, &c);
    bool  sm = th < 1e-6f;
    float a  = sm ? 1.0f : s / th;
    float b  = sm ? 0.5f : (1.0f - c) / th2;
    float cc = 1.0f - b * th2;
    R[0] = cc + b * v0 * v0;      R[1] = b * v0 * v1 - a * v2;  R[2] = b * v0 * v2 + a * v1;
    R[3] = b * v0 * v1 + a * v2;  R[4] = cc + b * v1 * v1;      R[5] = b * v1 * v2 - a * v0;
    R[6] = b * v0 * v2 - a * v1;  R[7] = b * v1 * v2 + a * v0;  R[8] = cc + b * v2 * v2;
}

// One element -> 3 float4 rows of [M | t], stored directly.
// Store pattern = R5's proven-clean 48-B lane-stride comb (WRITE_SIZE exact).
__device__ __forceinline__ void compute_store(
    const f3 t, const f3 r, const f3 u, const f3 s, float4* __restrict__ o)
{
    float R[9], U[9];
    rodrigues(r.x, r.y, r.z, R);
    rodrigues(u.x, u.y, u.z, U);
    const float d0 = expf(s.x), d1 = expf(s.y), d2 = expf(s.z);

    const float W0 = U[0]*d0, W1 = U[1]*d1, W2 = U[2]*d2;
    const float W3 = U[3]*d0, W4 = U[4]*d1, W5 = U[5]*d2;
    const float W6 = U[6]*d0, W7 = U[7]*d1, W8 = U[8]*d2;

    // S = W * U^T (symmetric — fp-identical to full 3x3, verified passing)
    const float S00 = W0*U[0] + W1*U[1] + W2*U[2];
    const float S01 = W0*U[3] + W1*U[4] + W2*U[5];
    const float S02 = W0*U[6] + W1*U[7] + W2*U[8];
    const float S11 = W3*U[3] + W4*U[4] + W5*U[5];
    const float S12 = W3*U[6] + W4*U[7] + W5*U[8];
    const float S22 = W6*U[6] + W7*U[7] + W8*U[8];

    // M = R * S
    const float M00 = R[0]*S00 + R[1]*S01 + R[2]*S02;
    const float M01 = R[0]*S01 + R[1]*S11 + R[2]*S12;
    const float M02 = R[0]*S02 + R[1]*S12 + R[2]*S22;
    const float M10 = R[3]*S00 + R[4]*S01 + R[5]*S02;
    const float M11 = R[3]*S01 + R[4]*S11 + R[5]*S12;
    const float M12 = R[3]*S02 + R[4]*S12 + R[5]*S22;
    const float M20 = R[6]*S00 + R[7]*S01 + R[8]*S02;
    const float M21 = R[6]*S01 + R[7]*S11 + R[8]*S12;
    const float M22 = R[6]*S02 + R[7]*S12 + R[8]*S22;

    o[0] = make_float4(M00, M01, M02, t.x);
    o[1] = make_float4(M10, M11, M12, t.y);
    o[2] = make_float4(M20, M21, M22, t.z);
}

// MLP-depth experiment: each thread owns NB=8 elements at stride TPB within its
// block's 2048-element span. ALL 32 dwordx3 loads (4 streams x 8 batches,
// 384 B/lane ~ 25 KB/wave) are issued before any compute — discriminates
// "2.35 TB/s service wall" (dur unchanged) vs "latency/MLP bound" (dur drops).
// Loads: wave covers 768 B contiguous per instr (R9: FETCH-clean).
// Stores: 48-B lane-stride comb per batch (R5: WRITE-clean). No LDS, no barriers.
__global__ __launch_bounds__(TPB) void aff_kernel(
    const f3* __restrict__ trans,
    const f3* __restrict__ rotat,
    const f3* __restrict__ sdir,
    const f3* __restrict__ scal,
    float4* __restrict__ out,
    int B)
{
    const int tid = threadIdx.x;
    const int E   = blockIdx.x * (TPB * NB);     // block's first element

    f3 t[NB], r[NB], u[NB], s[NB];
    bool g[NB];

    // ---- issue ALL loads upfront (fully unrolled, compile-time indices only) ----
#pragma unroll
    for (int b = 0; b < NB; ++b) {
        const int e = E + b * TPB + tid;
        g[b] = (e < B);
        if (g[b]) {
            t[b] = trans[e];
            r[b] = rotat[e];
            u[b] = sdir [e];
            s[b] = scal [e];
        } else {
            t[b] = f3{0.f,0.f,0.f}; r[b] = t[b]; u[b] = t[b]; s[b] = t[b];
        }
    }

    // ---- compute + direct store, batch by batch ----
#pragma unroll
    for (int b = 0; b < NB; ++b) {
        if (g[b]) {
            const int e = E + b * TPB + tid;
            compute_store(t[b], r[b], u[b], s[b], out + 3 * e);
        }
    }
}

extern "C" void kernel_launch(void* const* d_in, const int* in_sizes, int n_in,
                              void* d_out, int out_size, void* d_ws, size_t ws_size,
                              hipStream_t stream) {
    int B = in_sizes[0] / 3;                         // 2,000,000 elements
    int blocks = (B + TPB * NB - 1) / (TPB * NB);    // 977 blocks of 2048 elements
    aff_kernel<<<blocks, TPB, 0, stream>>>((const f3*)d_in[0], (const f3*)d_in[1],
                                           (const f3*)d_in[2], (const f3*)d_in[3],
                                           (float4*)d_out, B);
}